// Round 1
// baseline (1311.593 us; speedup 1.0000x reference)
//
#include <hip/hip_runtime.h>
#include <cmath>

#define NN 100000
#define EE 400000
#define ET (EE + NN)          // 500000 edges incl. self-loops
#define SLOPE 0.2f

// ---------------------------------------------------------------- CSR build
__global__ __launch_bounds__(256) void count_deg(const int* __restrict__ ei, int* __restrict__ deg) {
    int e = blockIdx.x * 256 + threadIdx.x;
    if (e < EE) atomicAdd(&deg[ei[EE + e]], 1);
}

// scan1: per-block (1024 elems) inclusive scan of (deg[n]+1)
__global__ __launch_bounds__(256) void scan1(const int* __restrict__ deg, int* __restrict__ incl,
                                             int* __restrict__ bsums) {
    __shared__ int ts[256];
    int b = blockIdx.x, t = threadIdx.x;
    int base = b * 1024 + t * 4;
    int v[4];
#pragma unroll
    for (int i = 0; i < 4; i++) {
        int n = base + i;
        v[i] = (n < NN) ? (deg[n] + 1) : 0;
    }
    int s = 0;
#pragma unroll
    for (int i = 0; i < 4; i++) { s += v[i]; v[i] = s; }   // thread-local inclusive
    ts[t] = s;
    __syncthreads();
    for (int off = 1; off < 256; off <<= 1) {
        int x = (t >= off) ? ts[t - off] : 0;
        __syncthreads();
        ts[t] += x;
        __syncthreads();
    }
    int excl = ts[t] - s;
#pragma unroll
    for (int i = 0; i < 4; i++) {
        int n = base + i;
        if (n < NN) incl[n] = v[i] + excl;
    }
    if (t == 255) bsums[b] = ts[255];
}

__global__ __launch_bounds__(128) void scan2(int* __restrict__ bsums, int nblk) {
    __shared__ int ts[128];
    int t = threadIdx.x;
    int v = (t < nblk) ? bsums[t] : 0;
    ts[t] = v;
    __syncthreads();
    for (int off = 1; off < 128; off <<= 1) {
        int x = (t >= off) ? ts[t - off] : 0;
        __syncthreads();
        ts[t] += x;
        __syncthreads();
    }
    if (t < nblk) bsums[t] = ts[t] - v;   // exclusive
}

__global__ __launch_bounds__(256) void scan3(const int* __restrict__ incl, const int* __restrict__ deg,
                                             const int* __restrict__ bsums, int* __restrict__ row_ptr,
                                             int* __restrict__ cursor) {
    int n = blockIdx.x * 256 + threadIdx.x;
    if (n < NN) {
        int rp = incl[n] - (deg[n] + 1) + bsums[n >> 10];
        row_ptr[n] = rp;
        cursor[n] = rp;
    }
    if (n == 0) row_ptr[NN] = ET;
}

__global__ __launch_bounds__(256) void scatter(const int* __restrict__ ei, int* __restrict__ cursor,
                                               int* __restrict__ col) {
    int e = blockIdx.x * 256 + threadIdx.x;
    if (e < EE) {
        int d = ei[EE + e];
        int p = atomicAdd(&cursor[d], 1);
        col[p] = ei[e];
    }
}

__global__ __launch_bounds__(256) void selfloop(const int* __restrict__ cursor, int* __restrict__ col) {
    int n = blockIdx.x * 256 + threadIdx.x;
    if (n < NN) col[cursor[n]] = n;   // last slot in each row
}

// ---------------------------------------------------------------- fp32 GEMM  C[M,Nc] = A[M,K] @ B[K,Nc]
// 64x64 tile, BK=32, 256 threads, 4x4 per thread
__global__ __launch_bounds__(256) void gemm64(const float* __restrict__ A, const float* __restrict__ B,
                                              float* __restrict__ C, int M, int K, int Nc) {
    __shared__ float As[32][65];   // pitch 65 -> 2-way max on stores (free)
    __shared__ float Bs[32][68];   // pitch 68 keeps float4 16B alignment
    int tid = threadIdx.x;
    int bm = blockIdx.x * 64;
    int bn = blockIdx.y * 64;
    int tx = tid & 15, ty = tid >> 4;
    float acc[4][4] = {};

    int ar = tid >> 2;             // 0..63 : A tile row
    int ac = (tid & 3) * 8;        // col group of 8
    int br = tid >> 3;             // 0..31 : B tile row
    int bc = (tid & 7) * 8;        // col group of 8

    for (int k0 = 0; k0 < K; k0 += 32) {
        // A tile (64 x 32), zero-fill rows >= M
        float a[8];
        if (bm + ar < M) {
            const float* ap = A + (size_t)(bm + ar) * K + k0 + ac;
            float4 a0 = *(const float4*)(ap);
            float4 a1 = *(const float4*)(ap + 4);
            a[0]=a0.x; a[1]=a0.y; a[2]=a0.z; a[3]=a0.w;
            a[4]=a1.x; a[5]=a1.y; a[6]=a1.z; a[7]=a1.w;
        } else {
#pragma unroll
            for (int j = 0; j < 8; j++) a[j] = 0.f;
        }
#pragma unroll
        for (int j = 0; j < 8; j++) As[ac + j][ar] = a[j];

        // B tile (32 x 64)
        const float* bp = B + (size_t)(k0 + br) * Nc + bn + bc;
        float4 b0 = *(const float4*)(bp);
        float4 b1 = *(const float4*)(bp + 4);
        *(float4*)&Bs[br][bc]     = b0;
        *(float4*)&Bs[br][bc + 4] = b1;

        __syncthreads();
#pragma unroll
        for (int k = 0; k < 32; k++) {
            float av[4], bv[4];
#pragma unroll
            for (int i = 0; i < 4; i++) av[i] = As[k][ty * 4 + i];
#pragma unroll
            for (int j = 0; j < 4; j++) bv[j] = Bs[k][tx * 4 + j];
#pragma unroll
            for (int i = 0; i < 4; i++)
#pragma unroll
                for (int j = 0; j < 4; j++) acc[i][j] += av[i] * bv[j];
        }
        __syncthreads();
    }
#pragma unroll
    for (int i = 0; i < 4; i++) {
        int row = bm + ty * 4 + i;
        if (row < M) {
#pragma unroll
            for (int j = 0; j < 4; j++)
                C[(size_t)row * Nc + bn + tx * 4 + j] = acc[i][j];
        }
    }
}

// ---------------------------------------------------------------- per-node attention scores
// block = HC threads, one node per block; head = C consecutive channels
__global__ void scores_k(const float* __restrict__ h, const float* __restrict__ a_s,
                         const float* __restrict__ a_d, float* __restrict__ als,
                         float* __restrict__ ald, int HC, int H) {
    int n = blockIdx.x;
    int t = threadIdx.x;
    float v = h[(size_t)n * HC + t];
    float s = v * a_s[t];
    float d = v * a_d[t];
#pragma unroll
    for (int off = 1; off < 64; off <<= 1) {
        s += __shfl_xor(s, off, 64);
        d += __shfl_xor(d, off, 64);
    }
    __shared__ float ps[8], pd[8];
    int w = t >> 6;
    if ((t & 63) == 0) { ps[w] = s; pd[w] = d; }
    __syncthreads();
    int wph = (HC / H) >> 6;   // waves per head (1 or 2)
    if (t < H) {
        float ss = 0.f, dd = 0.f;
        for (int i = 0; i < wph; i++) { ss += ps[t * wph + i]; dd += pd[t * wph + i]; }
        als[n * H + t] = ss;
        ald[n * H + t] = dd;
    }
}

// ---------------------------------------------------------------- CSR aggregation: one wave per (dst, head)
template <int C, int H, bool ELU_ACT>
__global__ __launch_bounds__(256) void aggregate(const float* __restrict__ hlin,
                                                 const float* __restrict__ als,
                                                 const float* __restrict__ ald,
                                                 const int* __restrict__ row_ptr,
                                                 const int* __restrict__ col,
                                                 const float* __restrict__ bias,
                                                 float* __restrict__ out) {
    const int HC = H * C;
    const int CPL = C / 64;
    int wid = blockIdx.x * 4 + (threadIdx.x >> 6);
    int lane = threadIdx.x & 63;
    int dst = wid / H, head = wid % H;
    if (dst >= NN) return;
    int rs = row_ptr[dst], re = row_ptr[dst + 1];
    float ad = ald[dst * H + head];

    // pass 1: segment max
    float m = -1e30f;
    for (int i = rs + lane; i < re; i += 64) {
        float s = als[col[i] * H + head] + ad;
        s = s > 0.f ? s : SLOPE * s;
        m = fmaxf(m, s);
    }
#pragma unroll
    for (int off = 1; off < 64; off <<= 1) m = fmaxf(m, __shfl_xor(m, off, 64));

    // pass 2: exp-sum
    float sum = 0.f;
    for (int i = rs + lane; i < re; i += 64) {
        float s = als[col[i] * H + head] + ad;
        s = s > 0.f ? s : SLOPE * s;
        sum += __expf(s - m);
    }
#pragma unroll
    for (int off = 1; off < 64; off <<= 1) sum += __shfl_xor(sum, off, 64);
    float inv = 1.0f / (sum + 1e-16f);

    // pass 3: weighted gather (coalesced 256B row reads)
    float acc[CPL];
#pragma unroll
    for (int j = 0; j < CPL; j++) acc[j] = 0.f;
    for (int i = rs; i < re; i++) {
        int src = col[i];                        // broadcast load
        float s = als[src * H + head] + ad;
        s = s > 0.f ? s : SLOPE * s;
        float w = __expf(s - m) * inv;
#pragma unroll
        for (int j = 0; j < CPL; j++)
            acc[j] += w * hlin[(size_t)src * HC + head * C + lane + j * 64];
    }
#pragma unroll
    for (int j = 0; j < CPL; j++) {
        float v = acc[j] + bias[head * C + lane + j * 64];
        if (ELU_ACT) v = v > 0.f ? v : (__expf(v) - 1.0f);
        out[(size_t)dst * HC + head * C + lane + j * 64] = v;
    }
}

// ---------------------------------------------------------------- launch
extern "C" void kernel_launch(void* const* d_in, const int* in_sizes, int n_in,
                              void* d_out, int out_size, void* d_ws, size_t ws_size,
                              hipStream_t stream) {
    const float* x   = (const float*)d_in[0];
    const int*   ei  = (const int*)d_in[1];
    const float* W0  = (const float*)d_in[2];
    const float* as0 = (const float*)d_in[3];
    const float* ad0 = (const float*)d_in[4];
    const float* b0  = (const float*)d_in[5];
    const float* W1  = (const float*)d_in[6];
    const float* as1 = (const float*)d_in[7];
    const float* ad1 = (const float*)d_in[8];
    const float* b1  = (const float*)d_in[9];
    const float* W2  = (const float*)d_in[10];
    const float* as2 = (const float*)d_in[11];
    const float* ad2 = (const float*)d_in[12];
    const float* b2  = (const float*)d_in[13];
    float* out = (float*)d_out;

    char* ws = (char*)d_ws;
    size_t off = 0;
    auto alloc = [&](size_t bytes) {
        void* p = ws + off;
        off += (bytes + 255) & ~(size_t)255;
        return p;
    };
    float* bufA    = (float*)alloc((size_t)NN * 256 * 4);
    float* bufB    = (float*)alloc((size_t)NN * 256 * 4);
    float* als     = (float*)alloc((size_t)NN * 4 * 4);
    float* ald     = (float*)alloc((size_t)NN * 4 * 4);
    int*   deg     = (int*)alloc((size_t)NN * 4);
    int*   incl    = (int*)alloc((size_t)NN * 4);
    int*   row_ptr = (int*)alloc((size_t)(NN + 1) * 4);
    int*   cursor  = (int*)alloc((size_t)NN * 4);
    int*   col     = (int*)alloc((size_t)ET * 4);
    int*   bsums   = (int*)alloc(128 * 4);

    const int NBLK = (NN + 1023) / 1024;   // 98

    // ---- CSR (shared by all layers)
    hipMemsetAsync(deg, 0, (size_t)NN * 4, stream);
    count_deg<<<(EE + 255) / 256, 256, 0, stream>>>(ei, deg);
    scan1<<<NBLK, 256, 0, stream>>>(deg, incl, bsums);
    scan2<<<1, 128, 0, stream>>>(bsums, NBLK);
    scan3<<<(NN + 255) / 256, 256, 0, stream>>>(incl, deg, bsums, row_ptr, cursor);
    scatter<<<(EE + 255) / 256, 256, 0, stream>>>(ei, cursor, col);
    selfloop<<<(NN + 255) / 256, 256, 0, stream>>>(cursor, col);

    const int MB = (NN + 63) / 64;   // 1563

    // ---- layer 0: x[N,128] @ W0[128,256] -> ELU(aggregate) -> bufB
    gemm64<<<dim3(MB, 4), 256, 0, stream>>>(x, W0, bufA, NN, 128, 256);
    scores_k<<<NN, 256, 0, stream>>>(bufA, as0, ad0, als, ald, 256, 4);
    aggregate<64, 4, true><<<NN, 256, 0, stream>>>(bufA, als, ald, row_ptr, col, b0, bufB);

    // ---- layer 1: bufB[N,256] @ W1[256,256] -> ELU(aggregate) -> bufB
    gemm64<<<dim3(MB, 4), 256, 0, stream>>>(bufB, W1, bufA, NN, 256, 256);
    scores_k<<<NN, 256, 0, stream>>>(bufA, as1, ad1, als, ald, 256, 4);
    aggregate<64, 4, true><<<NN, 256, 0, stream>>>(bufA, als, ald, row_ptr, col, b1, bufB);

    // ---- layer 2: bufB[N,256] @ W2[256,128] -> aggregate (1 head) -> out
    gemm64<<<dim3(MB, 2), 256, 0, stream>>>(bufB, W2, bufA, NN, 256, 128);
    scores_k<<<NN, 128, 0, stream>>>(bufA, as2, ad2, als, ald, 128, 1);
    aggregate<128, 1, false><<<(NN + 3) / 4, 256, 0, stream>>>(bufA, als, ald, row_ptr, col, b2, out);
}

// Round 2
// 1061.896 us; speedup vs baseline: 1.2351x; 1.2351x over previous
//
#include <hip/hip_runtime.h>
#include <cmath>

#define NN 100000
#define EE 400000
#define ET (EE + NN)          // 500000 edges incl. self-loops
#define SLOPE 0.2f

// ---------------------------------------------------------------- CSR build
__global__ __launch_bounds__(256) void count_deg(const int* __restrict__ ei, int* __restrict__ deg) {
    int e = blockIdx.x * 256 + threadIdx.x;
    if (e < EE) atomicAdd(&deg[ei[EE + e]], 1);
}

// scan1: per-block (1024 elems) inclusive scan of (deg[n]+1)
__global__ __launch_bounds__(256) void scan1(const int* __restrict__ deg, int* __restrict__ incl,
                                             int* __restrict__ bsums) {
    __shared__ int ts[256];
    int b = blockIdx.x, t = threadIdx.x;
    int base = b * 1024 + t * 4;
    int v[4];
#pragma unroll
    for (int i = 0; i < 4; i++) {
        int n = base + i;
        v[i] = (n < NN) ? (deg[n] + 1) : 0;
    }
    int s = 0;
#pragma unroll
    for (int i = 0; i < 4; i++) { s += v[i]; v[i] = s; }   // thread-local inclusive
    ts[t] = s;
    __syncthreads();
    for (int off = 1; off < 256; off <<= 1) {
        int x = (t >= off) ? ts[t - off] : 0;
        __syncthreads();
        ts[t] += x;
        __syncthreads();
    }
    int excl = ts[t] - s;
#pragma unroll
    for (int i = 0; i < 4; i++) {
        int n = base + i;
        if (n < NN) incl[n] = v[i] + excl;
    }
    if (t == 255) bsums[b] = ts[255];
}

__global__ __launch_bounds__(128) void scan2(int* __restrict__ bsums, int nblk) {
    __shared__ int ts[128];
    int t = threadIdx.x;
    int v = (t < nblk) ? bsums[t] : 0;
    ts[t] = v;
    __syncthreads();
    for (int off = 1; off < 128; off <<= 1) {
        int x = (t >= off) ? ts[t - off] : 0;
        __syncthreads();
        ts[t] += x;
        __syncthreads();
    }
    if (t < nblk) bsums[t] = ts[t] - v;   // exclusive
}

__global__ __launch_bounds__(256) void scan3(const int* __restrict__ incl, const int* __restrict__ deg,
                                             const int* __restrict__ bsums, int* __restrict__ row_ptr,
                                             int* __restrict__ cursor) {
    int n = blockIdx.x * 256 + threadIdx.x;
    if (n < NN) {
        int rp = incl[n] - (deg[n] + 1) + bsums[n >> 10];
        row_ptr[n] = rp;
        cursor[n] = rp;
    }
    if (n == 0) row_ptr[NN] = ET;
}

__global__ __launch_bounds__(256) void scatter(const int* __restrict__ ei, int* __restrict__ cursor,
                                               int* __restrict__ col) {
    int e = blockIdx.x * 256 + threadIdx.x;
    if (e < EE) {
        int d = ei[EE + e];
        int p = atomicAdd(&cursor[d], 1);
        col[p] = ei[e];
    }
}

__global__ __launch_bounds__(256) void selfloop(const int* __restrict__ cursor, int* __restrict__ col) {
    int n = blockIdx.x * 256 + threadIdx.x;
    if (n < NN) col[cursor[n]] = n;   // last slot in each row
}

// ---------------------------------------------------------------- fp32 GEMM  C[M,Nc] = A[M,K] @ B[K,Nc]
// 64x64 tile, BK=32, 256 threads, 4x4 per thread
__global__ __launch_bounds__(256) void gemm64(const float* __restrict__ A, const float* __restrict__ B,
                                              float* __restrict__ C, int M, int K, int Nc) {
    __shared__ float As[32][65];
    __shared__ float Bs[32][68];
    int tid = threadIdx.x;
    int bm = blockIdx.x * 64;
    int bn = blockIdx.y * 64;
    int tx = tid & 15, ty = tid >> 4;
    float acc[4][4] = {};

    int ar = tid >> 2;             // 0..63 : A tile row
    int ac = (tid & 3) * 8;        // col group of 8
    int br = tid >> 3;             // 0..31 : B tile row
    int bc = (tid & 7) * 8;        // col group of 8

    for (int k0 = 0; k0 < K; k0 += 32) {
        float a[8];
        if (bm + ar < M) {
            const float* ap = A + (size_t)(bm + ar) * K + k0 + ac;
            float4 a0 = *(const float4*)(ap);
            float4 a1 = *(const float4*)(ap + 4);
            a[0]=a0.x; a[1]=a0.y; a[2]=a0.z; a[3]=a0.w;
            a[4]=a1.x; a[5]=a1.y; a[6]=a1.z; a[7]=a1.w;
        } else {
#pragma unroll
            for (int j = 0; j < 8; j++) a[j] = 0.f;
        }
#pragma unroll
        for (int j = 0; j < 8; j++) As[ac + j][ar] = a[j];

        const float* bp = B + (size_t)(k0 + br) * Nc + bn + bc;
        float4 b0 = *(const float4*)(bp);
        float4 b1 = *(const float4*)(bp + 4);
        *(float4*)&Bs[br][bc]     = b0;
        *(float4*)&Bs[br][bc + 4] = b1;

        __syncthreads();
#pragma unroll
        for (int k = 0; k < 32; k++) {
            float av[4], bv[4];
#pragma unroll
            for (int i = 0; i < 4; i++) av[i] = As[k][ty * 4 + i];
#pragma unroll
            for (int j = 0; j < 4; j++) bv[j] = Bs[k][tx * 4 + j];
#pragma unroll
            for (int i = 0; i < 4; i++)
#pragma unroll
                for (int j = 0; j < 4; j++) acc[i][j] += av[i] * bv[j];
        }
        __syncthreads();
    }
#pragma unroll
    for (int i = 0; i < 4; i++) {
        int row = bm + ty * 4 + i;
        if (row < M) {
#pragma unroll
            for (int j = 0; j < 4; j++)
                C[(size_t)row * Nc + bn + tx * 4 + j] = acc[i][j];
        }
    }
}

// ---------------------------------------------------------------- per-node attention scores
__global__ void scores_k(const float* __restrict__ h, const float* __restrict__ a_s,
                         const float* __restrict__ a_d, float* __restrict__ als,
                         float* __restrict__ ald, int HC, int H) {
    int n = blockIdx.x;
    int t = threadIdx.x;
    float v = h[(size_t)n * HC + t];
    float s = v * a_s[t];
    float d = v * a_d[t];
#pragma unroll
    for (int off = 1; off < 64; off <<= 1) {
        s += __shfl_xor(s, off, 64);
        d += __shfl_xor(d, off, 64);
    }
    __shared__ float ps[8], pd[8];
    int w = t >> 6;
    if ((t & 63) == 0) { ps[w] = s; pd[w] = d; }
    __syncthreads();
    int wph = (HC / H) >> 6;   // waves per head (1 or 2)
    if (t < H) {
        float ss = 0.f, dd = 0.f;
        for (int i = 0; i < wph; i++) { ss += ps[t * wph + i]; dd += pd[t * wph + i]; }
        als[n * H + t] = ss;
        ald[n * H + t] = dd;
    }
}

// ---------------------------------------------------------------- CSR aggregation v2
// one wave per (dst, head); lane-parallel score gather + shfl-broadcast row loop
template <int C, int H, bool ELU_ACT>
__global__ __launch_bounds__(256) void aggregate(const float* __restrict__ hlin,
                                                 const float* __restrict__ als,
                                                 const float* __restrict__ ald,
                                                 const int* __restrict__ row_ptr,
                                                 const int* __restrict__ col,
                                                 const float* __restrict__ bias,
                                                 float* __restrict__ out) {
    const int HC = H * C;
    const int CPL = C / 64;
    int wid = blockIdx.x * 4 + (threadIdx.x >> 6);
    int lane = threadIdx.x & 63;
    int dst = wid / H, head = wid % H;
    if (dst >= NN) return;
    int rs = row_ptr[dst], re = row_ptr[dst + 1];
    int deg = re - rs;
    float ad = ald[dst * H + head];

    float acc[CPL];
#pragma unroll
    for (int j = 0; j < CPL; j++) acc[j] = 0.f;

    if (deg <= 64) {
        // lane i owns edge rs+i: one parallel gather for col+score
        int src = 0;
        float s = -1e30f;
        if (lane < deg) {
            src = col[rs + lane];
            s = als[src * H + head] + ad;
            s = s > 0.f ? s : SLOPE * s;
        }
        float m = s;
#pragma unroll
        for (int off = 1; off < 64; off <<= 1) m = fmaxf(m, __shfl_xor(m, off, 64));
        float e = (lane < deg) ? __expf(s - m) : 0.f;
        float sum = e;
#pragma unroll
        for (int off = 1; off < 64; off <<= 1) sum += __shfl_xor(sum, off, 64);
        float w = e * (1.0f / (sum + 1e-16f));

        // weighted gather: broadcast (src, w) from lane d; 4 loads in flight
        int d = 0;
        for (; d + 4 <= deg; d += 4) {
            int s0 = __shfl(src, d, 64),     s1 = __shfl(src, d + 1, 64);
            int s2 = __shfl(src, d + 2, 64), s3 = __shfl(src, d + 3, 64);
            float w0 = __shfl(w, d, 64),     w1 = __shfl(w, d + 1, 64);
            float w2 = __shfl(w, d + 2, 64), w3 = __shfl(w, d + 3, 64);
            const float* p0 = hlin + (size_t)s0 * HC + head * C + lane;
            const float* p1 = hlin + (size_t)s1 * HC + head * C + lane;
            const float* p2 = hlin + (size_t)s2 * HC + head * C + lane;
            const float* p3 = hlin + (size_t)s3 * HC + head * C + lane;
            float v0[CPL], v1[CPL], v2[CPL], v3[CPL];
#pragma unroll
            for (int j = 0; j < CPL; j++) { v0[j] = p0[j * 64]; v1[j] = p1[j * 64];
                                            v2[j] = p2[j * 64]; v3[j] = p3[j * 64]; }
#pragma unroll
            for (int j = 0; j < CPL; j++)
                acc[j] += w0 * v0[j] + w1 * v1[j] + w2 * v2[j] + w3 * v3[j];
        }
        for (; d < deg; d++) {
            int sd = __shfl(src, d, 64);
            float wd = __shfl(w, d, 64);
            const float* p = hlin + (size_t)sd * HC + head * C + lane;
#pragma unroll
            for (int j = 0; j < CPL; j++) acc[j] += wd * p[j * 64];
        }
    } else {
        // rare long-row fallback: 3-pass strided
        float m = -1e30f;
        for (int i = rs + lane; i < re; i += 64) {
            float s = als[col[i] * H + head] + ad;
            s = s > 0.f ? s : SLOPE * s;
            m = fmaxf(m, s);
        }
#pragma unroll
        for (int off = 1; off < 64; off <<= 1) m = fmaxf(m, __shfl_xor(m, off, 64));
        float sum = 0.f;
        for (int i = rs + lane; i < re; i += 64) {
            float s = als[col[i] * H + head] + ad;
            s = s > 0.f ? s : SLOPE * s;
            sum += __expf(s - m);
        }
#pragma unroll
        for (int off = 1; off < 64; off <<= 1) sum += __shfl_xor(sum, off, 64);
        float inv = 1.0f / (sum + 1e-16f);
        for (int i = rs; i < re; i++) {
            int src = col[i];
            float s = als[src * H + head] + ad;
            s = s > 0.f ? s : SLOPE * s;
            float wgt = __expf(s - m) * inv;
#pragma unroll
            for (int j = 0; j < CPL; j++)
                acc[j] += wgt * hlin[(size_t)src * HC + head * C + lane + j * 64];
        }
    }

#pragma unroll
    for (int j = 0; j < CPL; j++) {
        float v = acc[j] + bias[head * C + lane + j * 64];
        if (ELU_ACT) v = v > 0.f ? v : (__expf(v) - 1.0f);
        out[(size_t)dst * HC + head * C + lane + j * 64] = v;
    }
}

// ---------------------------------------------------------------- launch
extern "C" void kernel_launch(void* const* d_in, const int* in_sizes, int n_in,
                              void* d_out, int out_size, void* d_ws, size_t ws_size,
                              hipStream_t stream) {
    const float* x   = (const float*)d_in[0];
    const int*   ei  = (const int*)d_in[1];
    const float* W0  = (const float*)d_in[2];
    const float* as0 = (const float*)d_in[3];
    const float* ad0 = (const float*)d_in[4];
    const float* b0  = (const float*)d_in[5];
    const float* W1  = (const float*)d_in[6];
    const float* as1 = (const float*)d_in[7];
    const float* ad1 = (const float*)d_in[8];
    const float* b1  = (const float*)d_in[9];
    const float* W2  = (const float*)d_in[10];
    const float* as2 = (const float*)d_in[11];
    const float* ad2 = (const float*)d_in[12];
    const float* b2  = (const float*)d_in[13];
    float* out = (float*)d_out;

    char* ws = (char*)d_ws;
    size_t off = 0;
    auto alloc = [&](size_t bytes) {
        void* p = ws + off;
        off += (bytes + 255) & ~(size_t)255;
        return p;
    };
    float* bufA    = (float*)alloc((size_t)NN * 256 * 4);
    float* bufB    = (float*)alloc((size_t)NN * 256 * 4);
    float* als     = (float*)alloc((size_t)NN * 4 * 4);
    float* ald     = (float*)alloc((size_t)NN * 4 * 4);
    int*   deg     = (int*)alloc((size_t)NN * 4);
    int*   incl    = (int*)alloc((size_t)NN * 4);
    int*   row_ptr = (int*)alloc((size_t)(NN + 1) * 4);
    int*   cursor  = (int*)alloc((size_t)NN * 4);
    int*   col     = (int*)alloc((size_t)ET * 4);
    int*   bsums   = (int*)alloc(128 * 4);

    const int NBLK = (NN + 1023) / 1024;   // 98

    // ---- CSR (shared by all layers)
    hipMemsetAsync(deg, 0, (size_t)NN * 4, stream);
    count_deg<<<(EE + 255) / 256, 256, 0, stream>>>(ei, deg);
    scan1<<<NBLK, 256, 0, stream>>>(deg, incl, bsums);
    scan2<<<1, 128, 0, stream>>>(bsums, NBLK);
    scan3<<<(NN + 255) / 256, 256, 0, stream>>>(incl, deg, bsums, row_ptr, cursor);
    scatter<<<(EE + 255) / 256, 256, 0, stream>>>(ei, cursor, col);
    selfloop<<<(NN + 255) / 256, 256, 0, stream>>>(cursor, col);

    const int MB = (NN + 63) / 64;   // 1563

    // ---- layer 0: x[N,128] @ W0[128,256] -> ELU(aggregate) -> bufB
    gemm64<<<dim3(MB, 4), 256, 0, stream>>>(x, W0, bufA, NN, 128, 256);
    scores_k<<<NN, 256, 0, stream>>>(bufA, as0, ad0, als, ald, 256, 4);
    aggregate<64, 4, true><<<NN, 256, 0, stream>>>(bufA, als, ald, row_ptr, col, b0, bufB);

    // ---- layer 1: bufB[N,256] @ W1[256,256] -> ELU(aggregate) -> bufB
    gemm64<<<dim3(MB, 4), 256, 0, stream>>>(bufB, W1, bufA, NN, 256, 256);
    scores_k<<<NN, 256, 0, stream>>>(bufA, as1, ad1, als, ald, 256, 4);
    aggregate<64, 4, true><<<NN, 256, 0, stream>>>(bufA, als, ald, row_ptr, col, b1, bufB);

    // ---- layer 2: bufB[N,256] @ W2[256,128] -> aggregate (1 head) -> out
    gemm64<<<dim3(MB, 2), 256, 0, stream>>>(bufB, W2, bufA, NN, 256, 128);
    scores_k<<<NN, 128, 0, stream>>>(bufA, as2, ad2, als, ald, 128, 1);
    aggregate<128, 1, false><<<(NN + 3) / 4, 256, 0, stream>>>(bufA, als, ald, row_ptr, col, b2, out);
}

// Round 3
// 762.404 us; speedup vs baseline: 1.7203x; 1.3928x over previous
//
#include <hip/hip_runtime.h>
#include <cmath>

#define NN 100000
#define EE 400000
#define ET (EE + NN)          // 500000 edges incl. self-loops
#define SLOPE 0.2f

typedef __attribute__((ext_vector_type(8))) short short8;
typedef __attribute__((ext_vector_type(4))) float floatx4;

__device__ __forceinline__ float b2f(ushort u) {
    union { unsigned int i; float f; } v; v.i = ((unsigned int)u) << 16; return v.f;
}
__device__ __forceinline__ ushort f2b(float f) {
    union { float f; unsigned int i; } v; v.f = f;
    unsigned int r = v.i + 0x7FFFu + ((v.i >> 16) & 1u);   // RNE
    return (ushort)(r >> 16);
}

// ---------------------------------------------------------------- CSR build
__global__ __launch_bounds__(256) void count_deg(const int* __restrict__ ei, int* __restrict__ deg) {
    int e = blockIdx.x * 256 + threadIdx.x;
    if (e < EE) atomicAdd(&deg[ei[EE + e]], 1);
}

__global__ __launch_bounds__(256) void scan1(const int* __restrict__ deg, int* __restrict__ incl,
                                             int* __restrict__ bsums) {
    __shared__ int ts[256];
    int b = blockIdx.x, t = threadIdx.x;
    int base = b * 1024 + t * 4;
    int v[4];
#pragma unroll
    for (int i = 0; i < 4; i++) {
        int n = base + i;
        v[i] = (n < NN) ? (deg[n] + 1) : 0;
    }
    int s = 0;
#pragma unroll
    for (int i = 0; i < 4; i++) { s += v[i]; v[i] = s; }
    ts[t] = s;
    __syncthreads();
    for (int off = 1; off < 256; off <<= 1) {
        int x = (t >= off) ? ts[t - off] : 0;
        __syncthreads();
        ts[t] += x;
        __syncthreads();
    }
    int excl = ts[t] - s;
#pragma unroll
    for (int i = 0; i < 4; i++) {
        int n = base + i;
        if (n < NN) incl[n] = v[i] + excl;
    }
    if (t == 255) bsums[b] = ts[255];
}

__global__ __launch_bounds__(128) void scan2(int* __restrict__ bsums, int nblk) {
    __shared__ int ts[128];
    int t = threadIdx.x;
    int v = (t < nblk) ? bsums[t] : 0;
    ts[t] = v;
    __syncthreads();
    for (int off = 1; off < 128; off <<= 1) {
        int x = (t >= off) ? ts[t - off] : 0;
        __syncthreads();
        ts[t] += x;
        __syncthreads();
    }
    if (t < nblk) bsums[t] = ts[t] - v;
}

__global__ __launch_bounds__(256) void scan3(const int* __restrict__ incl, const int* __restrict__ deg,
                                             const int* __restrict__ bsums, int* __restrict__ row_ptr,
                                             int* __restrict__ cursor) {
    int n = blockIdx.x * 256 + threadIdx.x;
    if (n < NN) {
        int rp = incl[n] - (deg[n] + 1) + bsums[n >> 10];
        row_ptr[n] = rp;
        cursor[n] = rp;
    }
    if (n == 0) row_ptr[NN] = ET;
}

__global__ __launch_bounds__(256) void scatter(const int* __restrict__ ei, int* __restrict__ cursor,
                                               int* __restrict__ col) {
    int e = blockIdx.x * 256 + threadIdx.x;
    if (e < EE) {
        int d = ei[EE + e];
        int p = atomicAdd(&cursor[d], 1);
        col[p] = ei[e];
    }
}

__global__ __launch_bounds__(256) void selfloop(const int* __restrict__ cursor, int* __restrict__ col) {
    int n = blockIdx.x * 256 + threadIdx.x;
    if (n < NN) col[cursor[n]] = n;
}

// ---------------------------------------------------------------- casts
__global__ __launch_bounds__(256) void cast_to_bf16(const float* __restrict__ in,
                                                    ushort* __restrict__ out, int n4) {
    int i = blockIdx.x * 256 + threadIdx.x;
    if (i < n4) {
        float4 v = ((const float4*)in)[i];
        ushort4 o;
        o.x = f2b(v.x); o.y = f2b(v.y); o.z = f2b(v.z); o.w = f2b(v.w);
        ((ushort4*)out)[i] = o;
    }
}

// Wt[n*K + k] = bf16(W[k*N + n])
__global__ __launch_bounds__(256) void transpose_cast(const float* __restrict__ W,
                                                      ushort* __restrict__ Wt, int K, int N) {
    int idx = blockIdx.x * 256 + threadIdx.x;
    if (idx < N * K) {
        int n = idx / K, k = idx % K;
        Wt[idx] = f2b(W[(size_t)k * N + n]);
    }
}

// ---------------------------------------------------------------- bf16 MFMA GEMM
// C[M,N] bf16 = A[M,K] bf16 @ Bt[N,K]^T bf16, fp32 accum
// tile 128x128, BK=32, 256 threads = 4 waves (2x2), wave computes 64x64
#define LP 40   // LDS row pitch in bf16 elems (80 B, 16B-aligned, 20-bank stride)
__global__ __launch_bounds__(256) void gemm_bf16(const ushort* __restrict__ A,
                                                 const ushort* __restrict__ Bt,
                                                 ushort* __restrict__ C,
                                                 int M, int K, int N) {
    __shared__ ushort As[128 * LP];
    __shared__ ushort Bs[128 * LP];
    int tid = threadIdx.x;
    int bm = blockIdx.x * 128;
    int bn = blockIdx.y * 128;
    int wave = tid >> 6, lane = tid & 63;
    int wm = (wave >> 1) * 64, wn = (wave & 1) * 64;

    floatx4 acc[4][4];
#pragma unroll
    for (int i = 0; i < 4; i++)
#pragma unroll
        for (int j = 0; j < 4; j++) acc[i][j] = (floatx4)0.f;

    int r = tid >> 1;            // staging row 0..127
    int c = (tid & 1) * 16;      // col half: 0 or 16

    int frow = lane & 15;        // fragment row-in-tile
    int kq = (lane >> 4) * 8;    // fragment k offset (quad*8)

    for (int k0 = 0; k0 < K; k0 += 32) {
        uint4 a0, a1;
        if (bm + r < M) {
            const uint4* ap = (const uint4*)(A + (size_t)(bm + r) * K + k0 + c);
            a0 = ap[0]; a1 = ap[1];
        } else {
            a0 = make_uint4(0, 0, 0, 0); a1 = a0;
        }
        *(uint4*)&As[r * LP + c]     = a0;
        *(uint4*)&As[r * LP + c + 8] = a1;

        const uint4* bp = (const uint4*)(Bt + (size_t)(bn + r) * K + k0 + c);
        *(uint4*)&Bs[r * LP + c]     = bp[0];
        *(uint4*)&Bs[r * LP + c + 8] = bp[1];

        __syncthreads();

        short8 afr[4], bfr[4];
#pragma unroll
        for (int i = 0; i < 4; i++)
            afr[i] = *(const short8*)&As[(wm + i * 16 + frow) * LP + kq];
#pragma unroll
        for (int j = 0; j < 4; j++)
            bfr[j] = *(const short8*)&Bs[(wn + j * 16 + frow) * LP + kq];
#pragma unroll
        for (int i = 0; i < 4; i++)
#pragma unroll
            for (int j = 0; j < 4; j++)
                acc[i][j] = __builtin_amdgcn_mfma_f32_16x16x32_bf16(afr[i], bfr[j], acc[i][j], 0, 0, 0);

        __syncthreads();
    }

    // C write: row = quad*4+reg, col = lane&15  (verified m89 mapping)
    int ccol = bn + wn + (lane & 15);
    int crow = bm + wm + (lane >> 4) * 4;
#pragma unroll
    for (int i = 0; i < 4; i++) {
#pragma unroll
        for (int reg = 0; reg < 4; reg++) {
            int row = crow + i * 16 + reg;
            if (row < M) {
#pragma unroll
                for (int j = 0; j < 4; j++)
                    C[(size_t)row * N + ccol + j * 16] = f2b(acc[i][j][reg]);
            }
        }
    }
}

// ---------------------------------------------------------------- per-node attention scores (bf16 h)
__global__ void scores_k(const ushort* __restrict__ h, const float* __restrict__ a_s,
                         const float* __restrict__ a_d, float* __restrict__ als,
                         float* __restrict__ ald, int HC, int H) {
    int n = blockIdx.x;
    int t = threadIdx.x;
    float v = b2f(h[(size_t)n * HC + t]);
    float s = v * a_s[t];
    float d = v * a_d[t];
#pragma unroll
    for (int off = 1; off < 64; off <<= 1) {
        s += __shfl_xor(s, off, 64);
        d += __shfl_xor(d, off, 64);
    }
    __shared__ float ps[8], pd[8];
    int w = t >> 6;
    if ((t & 63) == 0) { ps[w] = s; pd[w] = d; }
    __syncthreads();
    int wph = (HC / H) >> 6;
    if (t < H) {
        float ss = 0.f, dd = 0.f;
        for (int i = 0; i < wph; i++) { ss += ps[t * wph + i]; dd += pd[t * wph + i]; }
        als[n * H + t] = ss;
        ald[n * H + t] = dd;
    }
}

// ---------------------------------------------------------------- CSR aggregation (bf16 h)
template <int C, int H, bool ELU_ACT, bool OUT_BF16>
__global__ __launch_bounds__(256) void aggregate(const ushort* __restrict__ hlin,
                                                 const float* __restrict__ als,
                                                 const float* __restrict__ ald,
                                                 const int* __restrict__ row_ptr,
                                                 const int* __restrict__ col,
                                                 const float* __restrict__ bias,
                                                 void* __restrict__ outv) {
    const int HC = H * C;
    const int CPL = C / 64;
    int wid = blockIdx.x * 4 + (threadIdx.x >> 6);
    int lane = threadIdx.x & 63;
    int dst = wid / H, head = wid % H;
    if (dst >= NN) return;
    int rs = row_ptr[dst], re = row_ptr[dst + 1];
    int deg = re - rs;
    float ad = ald[dst * H + head];

    float acc[CPL];
#pragma unroll
    for (int j = 0; j < CPL; j++) acc[j] = 0.f;

    if (deg <= 64) {
        int src = 0;
        float s = -1e30f;
        if (lane < deg) {
            src = col[rs + lane];
            s = als[src * H + head] + ad;
            s = s > 0.f ? s : SLOPE * s;
        }
        float m = s;
#pragma unroll
        for (int off = 1; off < 64; off <<= 1) m = fmaxf(m, __shfl_xor(m, off, 64));
        float e = (lane < deg) ? __expf(s - m) : 0.f;
        float sum = e;
#pragma unroll
        for (int off = 1; off < 64; off <<= 1) sum += __shfl_xor(sum, off, 64);
        float w = e * (1.0f / (sum + 1e-16f));

        int d = 0;
        for (; d + 4 <= deg; d += 4) {
            int s0 = __shfl(src, d, 64),     s1 = __shfl(src, d + 1, 64);
            int s2 = __shfl(src, d + 2, 64), s3 = __shfl(src, d + 3, 64);
            float w0 = __shfl(w, d, 64),     w1 = __shfl(w, d + 1, 64);
            float w2 = __shfl(w, d + 2, 64), w3 = __shfl(w, d + 3, 64);
            const ushort* p0 = hlin + (size_t)s0 * HC + head * C + lane;
            const ushort* p1 = hlin + (size_t)s1 * HC + head * C + lane;
            const ushort* p2 = hlin + (size_t)s2 * HC + head * C + lane;
            const ushort* p3 = hlin + (size_t)s3 * HC + head * C + lane;
            float v0[CPL], v1[CPL], v2[CPL], v3[CPL];
#pragma unroll
            for (int j = 0; j < CPL; j++) { v0[j] = b2f(p0[j * 64]); v1[j] = b2f(p1[j * 64]);
                                            v2[j] = b2f(p2[j * 64]); v3[j] = b2f(p3[j * 64]); }
#pragma unroll
            for (int j = 0; j < CPL; j++)
                acc[j] += w0 * v0[j] + w1 * v1[j] + w2 * v2[j] + w3 * v3[j];
        }
        for (; d < deg; d++) {
            int sd = __shfl(src, d, 64);
            float wd = __shfl(w, d, 64);
            const ushort* p = hlin + (size_t)sd * HC + head * C + lane;
#pragma unroll
            for (int j = 0; j < CPL; j++) acc[j] += wd * b2f(p[j * 64]);
        }
    } else {
        float m = -1e30f;
        for (int i = rs + lane; i < re; i += 64) {
            float s = als[col[i] * H + head] + ad;
            s = s > 0.f ? s : SLOPE * s;
            m = fmaxf(m, s);
        }
#pragma unroll
        for (int off = 1; off < 64; off <<= 1) m = fmaxf(m, __shfl_xor(m, off, 64));
        float sum = 0.f;
        for (int i = rs + lane; i < re; i += 64) {
            float s = als[col[i] * H + head] + ad;
            s = s > 0.f ? s : SLOPE * s;
            sum += __expf(s - m);
        }
#pragma unroll
        for (int off = 1; off < 64; off <<= 1) sum += __shfl_xor(sum, off, 64);
        float inv = 1.0f / (sum + 1e-16f);
        for (int i = rs; i < re; i++) {
            int src = col[i];
            float s = als[src * H + head] + ad;
            s = s > 0.f ? s : SLOPE * s;
            float wgt = __expf(s - m) * inv;
#pragma unroll
            for (int j = 0; j < CPL; j++)
                acc[j] += wgt * b2f(hlin[(size_t)src * HC + head * C + lane + j * 64]);
        }
    }

#pragma unroll
    for (int j = 0; j < CPL; j++) {
        float v = acc[j] + bias[head * C + lane + j * 64];
        if (ELU_ACT) v = v > 0.f ? v : (__expf(v) - 1.0f);
        size_t oi = (size_t)dst * HC + head * C + lane + j * 64;
        if (OUT_BF16) ((ushort*)outv)[oi] = f2b(v);
        else          ((float*)outv)[oi] = v;
    }
}

// ---------------------------------------------------------------- launch
extern "C" void kernel_launch(void* const* d_in, const int* in_sizes, int n_in,
                              void* d_out, int out_size, void* d_ws, size_t ws_size,
                              hipStream_t stream) {
    const float* x   = (const float*)d_in[0];
    const int*   ei  = (const int*)d_in[1];
    const float* W0  = (const float*)d_in[2];
    const float* as0 = (const float*)d_in[3];
    const float* ad0 = (const float*)d_in[4];
    const float* b0  = (const float*)d_in[5];
    const float* W1  = (const float*)d_in[6];
    const float* as1 = (const float*)d_in[7];
    const float* ad1 = (const float*)d_in[8];
    const float* b1  = (const float*)d_in[9];
    const float* W2  = (const float*)d_in[10];
    const float* as2 = (const float*)d_in[11];
    const float* ad2 = (const float*)d_in[12];
    const float* b2  = (const float*)d_in[13];
    float* out = (float*)d_out;

    char* ws = (char*)d_ws;
    size_t off = 0;
    auto alloc = [&](size_t bytes) {
        void* p = ws + off;
        off += (bytes + 255) & ~(size_t)255;
        return p;
    };
    ushort* xb   = (ushort*)alloc((size_t)NN * 128 * 2);   // 25.6 MB
    ushort* h    = (ushort*)alloc((size_t)NN * 256 * 2);   // 51.2 MB
    ushort* actB = (ushort*)alloc((size_t)NN * 256 * 2);   // 51.2 MB
    ushort* actC = (ushort*)alloc((size_t)NN * 256 * 2);   // 51.2 MB
    ushort* Wt0  = (ushort*)alloc((size_t)256 * 128 * 2);
    ushort* Wt1  = (ushort*)alloc((size_t)256 * 256 * 2);
    ushort* Wt2  = (ushort*)alloc((size_t)128 * 256 * 2);
    float* als   = (float*)alloc((size_t)NN * 4 * 4);
    float* ald   = (float*)alloc((size_t)NN * 4 * 4);
    int* deg     = (int*)alloc((size_t)NN * 4);
    int* incl    = (int*)alloc((size_t)NN * 4);
    int* row_ptr = (int*)alloc((size_t)(NN + 1) * 4);
    int* cursor  = (int*)alloc((size_t)NN * 4);
    int* col     = (int*)alloc((size_t)ET * 4);
    int* bsums   = (int*)alloc(128 * 4);

    const int NBLK = (NN + 1023) / 1024;   // 98

    // ---- CSR (shared by all layers)
    hipMemsetAsync(deg, 0, (size_t)NN * 4, stream);
    count_deg<<<(EE + 255) / 256, 256, 0, stream>>>(ei, deg);
    scan1<<<NBLK, 256, 0, stream>>>(deg, incl, bsums);
    scan2<<<1, 128, 0, stream>>>(bsums, NBLK);
    scan3<<<(NN + 255) / 256, 256, 0, stream>>>(incl, deg, bsums, row_ptr, cursor);
    scatter<<<(EE + 255) / 256, 256, 0, stream>>>(ei, cursor, col);
    selfloop<<<(NN + 255) / 256, 256, 0, stream>>>(cursor, col);

    // ---- bf16 conversions
    cast_to_bf16<<<(NN * 128 / 4 + 255) / 256, 256, 0, stream>>>(x, xb, NN * 128 / 4);
    transpose_cast<<<(256 * 128 + 255) / 256, 256, 0, stream>>>(W0, Wt0, 128, 256);
    transpose_cast<<<(256 * 256 + 255) / 256, 256, 0, stream>>>(W1, Wt1, 256, 256);
    transpose_cast<<<(128 * 256 + 255) / 256, 256, 0, stream>>>(W2, Wt2, 256, 128);

    const int GM = (NN + 127) / 128;   // 782

    // ---- layer 0: xb[N,128] @ W0 -> h[N,256]; aggregate+ELU -> actB (bf16)
    gemm_bf16<<<dim3(GM, 2), 256, 0, stream>>>(xb, Wt0, h, NN, 128, 256);
    scores_k<<<NN, 256, 0, stream>>>(h, as0, ad0, als, ald, 256, 4);
    aggregate<64, 4, true, true><<<NN, 256, 0, stream>>>(h, als, ald, row_ptr, col, b0, actB);

    // ---- layer 1
    gemm_bf16<<<dim3(GM, 2), 256, 0, stream>>>(actB, Wt1, h, NN, 256, 256);
    scores_k<<<NN, 256, 0, stream>>>(h, as1, ad1, als, ald, 256, 4);
    aggregate<64, 4, true, true><<<NN, 256, 0, stream>>>(h, als, ald, row_ptr, col, b1, actC);

    // ---- layer 2: actC[N,256] @ W2 -> h[N,128]; aggregate (1 head) -> out fp32
    gemm_bf16<<<dim3(GM, 1), 256, 0, stream>>>(actC, Wt2, h, NN, 256, 128);
    scores_k<<<NN, 128, 0, stream>>>(h, as2, ad2, als, ald, 128, 1);
    aggregate<128, 1, false, false><<<(NN + 3) / 4, 256, 0, stream>>>(h, als, ald, row_ptr, col, b2, out);
}

// Round 4
// 470.923 us; speedup vs baseline: 2.7852x; 1.6190x over previous
//
#include <hip/hip_runtime.h>
#include <cmath>

#define NN 100000
#define EE 400000
#define ET (EE + NN)          // 500000 edges incl. self-loops
#define SLOPE 0.2f

typedef __attribute__((ext_vector_type(8))) short short8;
typedef __attribute__((ext_vector_type(4))) float floatx4;

__device__ __forceinline__ float b2f(ushort u) {
    union { unsigned int i; float f; } v; v.i = ((unsigned int)u) << 16; return v.f;
}
__device__ __forceinline__ ushort f2b(float f) {
    union { float f; unsigned int i; } v; v.f = f;
    unsigned int r = v.i + 0x7FFFu + ((v.i >> 16) & 1u);   // RNE
    return (ushort)(r >> 16);
}

// ---------------------------------------------------------------- CSR build
__global__ __launch_bounds__(256) void count_deg(const int* __restrict__ ei, int* __restrict__ deg) {
    int e = blockIdx.x * 256 + threadIdx.x;
    if (e < EE) atomicAdd(&deg[ei[EE + e]], 1);
}

__global__ __launch_bounds__(256) void scan1(const int* __restrict__ deg, int* __restrict__ incl,
                                             int* __restrict__ bsums) {
    __shared__ int ts[256];
    int b = blockIdx.x, t = threadIdx.x;
    int base = b * 1024 + t * 4;
    int v[4];
#pragma unroll
    for (int i = 0; i < 4; i++) {
        int n = base + i;
        v[i] = (n < NN) ? (deg[n] + 1) : 0;
    }
    int s = 0;
#pragma unroll
    for (int i = 0; i < 4; i++) { s += v[i]; v[i] = s; }
    ts[t] = s;
    __syncthreads();
    for (int off = 1; off < 256; off <<= 1) {
        int x = (t >= off) ? ts[t - off] : 0;
        __syncthreads();
        ts[t] += x;
        __syncthreads();
    }
    int excl = ts[t] - s;
#pragma unroll
    for (int i = 0; i < 4; i++) {
        int n = base + i;
        if (n < NN) incl[n] = v[i] + excl;
    }
    if (t == 255) bsums[b] = ts[255];
}

__global__ __launch_bounds__(128) void scan2(int* __restrict__ bsums, int nblk) {
    __shared__ int ts[128];
    int t = threadIdx.x;
    int v = (t < nblk) ? bsums[t] : 0;
    ts[t] = v;
    __syncthreads();
    for (int off = 1; off < 128; off <<= 1) {
        int x = (t >= off) ? ts[t - off] : 0;
        __syncthreads();
        ts[t] += x;
        __syncthreads();
    }
    if (t < nblk) bsums[t] = ts[t] - v;
}

__global__ __launch_bounds__(256) void scan3(const int* __restrict__ incl, const int* __restrict__ deg,
                                             const int* __restrict__ bsums, int* __restrict__ row_ptr,
                                             int* __restrict__ cursor) {
    int n = blockIdx.x * 256 + threadIdx.x;
    if (n < NN) {
        int rp = incl[n] - (deg[n] + 1) + bsums[n >> 10];
        row_ptr[n] = rp;
        cursor[n] = rp;
    }
    if (n == 0) row_ptr[NN] = ET;
}

__global__ __launch_bounds__(256) void scatter(const int* __restrict__ ei, int* __restrict__ cursor,
                                               int* __restrict__ col) {
    int e = blockIdx.x * 256 + threadIdx.x;
    if (e < EE) {
        int d = ei[EE + e];
        int p = atomicAdd(&cursor[d], 1);
        col[p] = ei[e];
    }
}

__global__ __launch_bounds__(256) void selfloop(const int* __restrict__ cursor, int* __restrict__ col) {
    int n = blockIdx.x * 256 + threadIdx.x;
    if (n < NN) col[cursor[n]] = n;
}

// ---------------------------------------------------------------- casts
__global__ __launch_bounds__(256) void cast_to_bf16(const float* __restrict__ in,
                                                    ushort* __restrict__ out, int n4) {
    int i = blockIdx.x * 256 + threadIdx.x;
    if (i < n4) {
        float4 v = ((const float4*)in)[i];
        ushort4 o;
        o.x = f2b(v.x); o.y = f2b(v.y); o.z = f2b(v.z); o.w = f2b(v.w);
        ((ushort4*)out)[i] = o;
    }
}

// Wt[n*K + k] = bf16(W[k*N + n])
__global__ __launch_bounds__(256) void transpose_cast(const float* __restrict__ W,
                                                      ushort* __restrict__ Wt, int K, int N) {
    int idx = blockIdx.x * 256 + threadIdx.x;
    if (idx < N * K) {
        int n = idx / K, k = idx % K;
        Wt[idx] = f2b(W[(size_t)k * N + n]);
    }
}

// ---------------------------------------------------------------- bf16 MFMA GEMM
// C[M,N] bf16 = A[M,K] bf16 @ Bt[N,K]^T bf16, fp32 accum
// tile 128x128, BK=32, 256 threads = 4 waves (2x2), wave computes 64x64
#define LP 40   // LDS row pitch in bf16 elems (80 B, 16B-aligned)
__global__ __launch_bounds__(256) void gemm_bf16(const ushort* __restrict__ A,
                                                 const ushort* __restrict__ Bt,
                                                 ushort* __restrict__ C,
                                                 int M, int K, int N) {
    __shared__ ushort As[128 * LP];
    __shared__ ushort Bs[128 * LP];
    int tid = threadIdx.x;
    int bm = blockIdx.x * 128;
    int bn = blockIdx.y * 128;
    int wave = tid >> 6, lane = tid & 63;
    int wm = (wave >> 1) * 64, wn = (wave & 1) * 64;

    floatx4 acc[4][4];
#pragma unroll
    for (int i = 0; i < 4; i++)
#pragma unroll
        for (int j = 0; j < 4; j++) acc[i][j] = (floatx4)0.f;

    int r = tid >> 1;            // staging row 0..127
    int c = (tid & 1) * 16;      // col half: 0 or 16

    int frow = lane & 15;
    int kq = (lane >> 4) * 8;

    for (int k0 = 0; k0 < K; k0 += 32) {
        uint4 a0, a1;
        if (bm + r < M) {
            const uint4* ap = (const uint4*)(A + (size_t)(bm + r) * K + k0 + c);
            a0 = ap[0]; a1 = ap[1];
        } else {
            a0 = make_uint4(0, 0, 0, 0); a1 = a0;
        }
        *(uint4*)&As[r * LP + c]     = a0;
        *(uint4*)&As[r * LP + c + 8] = a1;

        const uint4* bp = (const uint4*)(Bt + (size_t)(bn + r) * K + k0 + c);
        *(uint4*)&Bs[r * LP + c]     = bp[0];
        *(uint4*)&Bs[r * LP + c + 8] = bp[1];

        __syncthreads();

        short8 afr[4], bfr[4];
#pragma unroll
        for (int i = 0; i < 4; i++)
            afr[i] = *(const short8*)&As[(wm + i * 16 + frow) * LP + kq];
#pragma unroll
        for (int j = 0; j < 4; j++)
            bfr[j] = *(const short8*)&Bs[(wn + j * 16 + frow) * LP + kq];
#pragma unroll
        for (int i = 0; i < 4; i++)
#pragma unroll
            for (int j = 0; j < 4; j++)
                acc[i][j] = __builtin_amdgcn_mfma_f32_16x16x32_bf16(afr[i], bfr[j], acc[i][j], 0, 0, 0);

        __syncthreads();
    }

    int ccol = bn + wn + (lane & 15);
    int crow = bm + wm + (lane >> 4) * 4;
#pragma unroll
    for (int i = 0; i < 4; i++) {
#pragma unroll
        for (int reg = 0; reg < 4; reg++) {
            int row = crow + i * 16 + reg;
            if (row < M) {
#pragma unroll
                for (int j = 0; j < 4; j++)
                    C[(size_t)row * N + ccol + j * 16] = f2b(acc[i][j][reg]);
            }
        }
    }
}

// ---------------------------------------------------------------- per-node attention scores
// one wave per node; lane covers CP=HC/64 channels (uint loads); 64/H-lane group reduce
template <int H, int HC>
__global__ __launch_bounds__(256) void scores_k(const ushort* __restrict__ h,
                                                const float* __restrict__ a_s,
                                                const float* __restrict__ a_d,
                                                float* __restrict__ als,
                                                float* __restrict__ ald) {
    constexpr int CP = HC / 64;       // channels per lane
    constexpr int GS = 64 / H;        // lanes per head
    int wv = threadIdx.x >> 6, lane = threadIdx.x & 63;
    int n = blockIdx.x * 4 + wv;
    if (n >= NN) return;
    const uint* p = (const uint*)(h + (size_t)n * HC + lane * CP);
    float s = 0.f, d = 0.f;
#pragma unroll
    for (int q = 0; q < CP / 2; q++) {
        uint u = p[q];
        int ch = lane * CP + 2 * q;
        float v0 = b2f((ushort)(u & 0xffff)), v1 = b2f((ushort)(u >> 16));
        s += v0 * a_s[ch] + v1 * a_s[ch + 1];
        d += v0 * a_d[ch] + v1 * a_d[ch + 1];
    }
#pragma unroll
    for (int off = 1; off < GS; off <<= 1) {
        s += __shfl_xor(s, off, 64);
        d += __shfl_xor(d, off, 64);
    }
    if ((lane & (GS - 1)) == 0) {
        int head = lane / GS;
        als[n * H + head] = s;
        ald[n * H + head] = d;
    }
}

// ---------------------------------------------------------------- CSR aggregation v3
// ONE WAVE PER DST NODE, all heads together.
// lane = head*GS + edge-slot for scoring; lane covers CP channels for gathering.
template <int H, int HC, bool ELU_ACT, bool OUT_BF16>
__global__ __launch_bounds__(256) void aggregate(const ushort* __restrict__ hlin,
                                                 const float* __restrict__ als,
                                                 const float* __restrict__ ald,
                                                 const int* __restrict__ row_ptr,
                                                 const int* __restrict__ col,
                                                 const float* __restrict__ bias,
                                                 void* __restrict__ outv) {
    constexpr int CP = HC / 64;       // channels per lane (4 or 2)
    constexpr int GS = 64 / H;        // lanes per head group (16 or 64)
    int wv = threadIdx.x >> 6, lane = threadIdx.x & 63;
    int dst = blockIdx.x * 4 + wv;
    if (dst >= NN) return;
    int rs = row_ptr[dst], re = row_ptr[dst + 1];
    int deg = re - rs;
    int eg = lane & (GS - 1);         // edge slot within group
    int head = lane / GS;
    float ad = ald[dst * H + head];

    float acc[CP];
#pragma unroll
    for (int j = 0; j < CP; j++) acc[j] = 0.f;

    uint laneoff = (uint)(lane * CP);

    if (deg <= GS) {
        // ---- fast path: lane slot eg owns edge eg
        int src = 0;
        float s = -1e30f;
        if (eg < deg) {
            src = col[rs + eg];
            float sc = als[src * H + head] + ad;
            s = sc > 0.f ? sc : SLOPE * sc;
        }
        float m = s;
#pragma unroll
        for (int off = 1; off < GS; off <<= 1) m = fmaxf(m, __shfl_xor(m, off, 64));
        float e = (eg < deg) ? __expf(s - m) : 0.f;
        float sum = e;
#pragma unroll
        for (int off = 1; off < GS; off <<= 1) sum += __shfl_xor(sum, off, 64);
        float w = e * (1.0f / (sum + 1e-16f));

        int hbase = head * GS;        // broadcast source base for weights
        int d = 0;
        for (; d + 4 <= deg; d += 4) {
            int s0 = __shfl(src, d, 64),     s1 = __shfl(src, d + 1, 64);
            int s2 = __shfl(src, d + 2, 64), s3 = __shfl(src, d + 3, 64);
            float w0 = __shfl(w, hbase + d, 64),     w1 = __shfl(w, hbase + d + 1, 64);
            float w2 = __shfl(w, hbase + d + 2, 64), w3 = __shfl(w, hbase + d + 3, 64);
            const uint* p0 = (const uint*)(hlin + (uint)s0 * HC + laneoff);
            const uint* p1 = (const uint*)(hlin + (uint)s1 * HC + laneoff);
            const uint* p2 = (const uint*)(hlin + (uint)s2 * HC + laneoff);
            const uint* p3 = (const uint*)(hlin + (uint)s3 * HC + laneoff);
            uint u0[CP / 2], u1[CP / 2], u2[CP / 2], u3[CP / 2];
#pragma unroll
            for (int q = 0; q < CP / 2; q++) { u0[q] = p0[q]; u1[q] = p1[q]; u2[q] = p2[q]; u3[q] = p3[q]; }
#pragma unroll
            for (int q = 0; q < CP / 2; q++) {
                acc[2*q]   += w0 * b2f((ushort)(u0[q] & 0xffff)) + w1 * b2f((ushort)(u1[q] & 0xffff))
                            + w2 * b2f((ushort)(u2[q] & 0xffff)) + w3 * b2f((ushort)(u3[q] & 0xffff));
                acc[2*q+1] += w0 * b2f((ushort)(u0[q] >> 16)) + w1 * b2f((ushort)(u1[q] >> 16))
                            + w2 * b2f((ushort)(u2[q] >> 16)) + w3 * b2f((ushort)(u3[q] >> 16));
            }
        }
        for (; d < deg; d++) {
            int sd = __shfl(src, d, 64);
            float wd = __shfl(w, hbase + d, 64);
            const uint* p = (const uint*)(hlin + (uint)sd * HC + laneoff);
#pragma unroll
            for (int q = 0; q < CP / 2; q++) {
                uint u = p[q];
                acc[2*q]   += wd * b2f((ushort)(u & 0xffff));
                acc[2*q+1] += wd * b2f((ushort)(u >> 16));
            }
        }
    } else {
        // ---- rare long-row path
        float m = -1e30f;
        for (int e2 = eg; e2 < deg; e2 += GS) {
            int sc0 = col[rs + e2];
            float sc = als[sc0 * H + head] + ad;
            sc = sc > 0.f ? sc : SLOPE * sc;
            m = fmaxf(m, sc);
        }
#pragma unroll
        for (int off = 1; off < GS; off <<= 1) m = fmaxf(m, __shfl_xor(m, off, 64));
        float sum = 0.f;
        for (int e2 = eg; e2 < deg; e2 += GS) {
            int sc0 = col[rs + e2];
            float sc = als[sc0 * H + head] + ad;
            sc = sc > 0.f ? sc : SLOPE * sc;
            sum += __expf(sc - m);
        }
#pragma unroll
        for (int off = 1; off < GS; off <<= 1) sum += __shfl_xor(sum, off, 64);
        float inv = 1.0f / (sum + 1e-16f);
        for (int d = 0; d < deg; d++) {
            int sd = col[rs + d];                 // uniform
            float sc = als[sd * H + head] + ad;
            sc = sc > 0.f ? sc : SLOPE * sc;
            float wd = __expf(sc - m) * inv;
            const uint* p = (const uint*)(hlin + (uint)sd * HC + laneoff);
#pragma unroll
            for (int q = 0; q < CP / 2; q++) {
                uint u = p[q];
                acc[2*q]   += wd * b2f((ushort)(u & 0xffff));
                acc[2*q+1] += wd * b2f((ushort)(u >> 16));
            }
        }
    }

    // epilogue: bias (+ ELU) and store
#pragma unroll
    for (int j = 0; j < CP; j++) {
        float v = acc[j] + bias[lane * CP + j];
        if (ELU_ACT) v = v > 0.f ? v : (__expf(v) - 1.0f);
        acc[j] = v;
    }
    if (OUT_BF16) {
        ushort* outp = (ushort*)outv + (size_t)dst * HC + laneoff;
        uint pk[CP / 2];
#pragma unroll
        for (int q = 0; q < CP / 2; q++)
            pk[q] = (uint)f2b(acc[2*q]) | ((uint)f2b(acc[2*q+1]) << 16);
#pragma unroll
        for (int q = 0; q < CP / 2; q++) ((uint*)outp)[q] = pk[q];
    } else {
        float* outp = (float*)outv + (size_t)dst * HC + laneoff;
#pragma unroll
        for (int j = 0; j < CP; j++) outp[j] = acc[j];
    }
}

// ---------------------------------------------------------------- launch
extern "C" void kernel_launch(void* const* d_in, const int* in_sizes, int n_in,
                              void* d_out, int out_size, void* d_ws, size_t ws_size,
                              hipStream_t stream) {
    const float* x   = (const float*)d_in[0];
    const int*   ei  = (const int*)d_in[1];
    const float* W0  = (const float*)d_in[2];
    const float* as0 = (const float*)d_in[3];
    const float* ad0 = (const float*)d_in[4];
    const float* b0  = (const float*)d_in[5];
    const float* W1  = (const float*)d_in[6];
    const float* as1 = (const float*)d_in[7];
    const float* ad1 = (const float*)d_in[8];
    const float* b1  = (const float*)d_in[9];
    const float* W2  = (const float*)d_in[10];
    const float* as2 = (const float*)d_in[11];
    const float* ad2 = (const float*)d_in[12];
    const float* b2  = (const float*)d_in[13];
    float* out = (float*)d_out;

    char* ws = (char*)d_ws;
    size_t off = 0;
    auto alloc = [&](size_t bytes) {
        void* p = ws + off;
        off += (bytes + 255) & ~(size_t)255;
        return p;
    };
    ushort* xb   = (ushort*)alloc((size_t)NN * 128 * 2);
    ushort* h    = (ushort*)alloc((size_t)NN * 256 * 2);
    ushort* actB = (ushort*)alloc((size_t)NN * 256 * 2);
    ushort* actC = (ushort*)alloc((size_t)NN * 256 * 2);
    ushort* Wt0  = (ushort*)alloc((size_t)256 * 128 * 2);
    ushort* Wt1  = (ushort*)alloc((size_t)256 * 256 * 2);
    ushort* Wt2  = (ushort*)alloc((size_t)128 * 256 * 2);
    float* als   = (float*)alloc((size_t)NN * 4 * 4);
    float* ald   = (float*)alloc((size_t)NN * 4 * 4);
    int* deg     = (int*)alloc((size_t)NN * 4);
    int* incl    = (int*)alloc((size_t)NN * 4);
    int* row_ptr = (int*)alloc((size_t)(NN + 1) * 4);
    int* cursor  = (int*)alloc((size_t)NN * 4);
    int* col     = (int*)alloc((size_t)ET * 4);
    int* bsums   = (int*)alloc(128 * 4);

    const int NBLK = (NN + 1023) / 1024;   // 98

    // ---- CSR (shared by all layers)
    hipMemsetAsync(deg, 0, (size_t)NN * 4, stream);
    count_deg<<<(EE + 255) / 256, 256, 0, stream>>>(ei, deg);
    scan1<<<NBLK, 256, 0, stream>>>(deg, incl, bsums);
    scan2<<<1, 128, 0, stream>>>(bsums, NBLK);
    scan3<<<(NN + 255) / 256, 256, 0, stream>>>(incl, deg, bsums, row_ptr, cursor);
    scatter<<<(EE + 255) / 256, 256, 0, stream>>>(ei, cursor, col);
    selfloop<<<(NN + 255) / 256, 256, 0, stream>>>(cursor, col);

    // ---- bf16 conversions
    cast_to_bf16<<<(NN * 128 / 4 + 255) / 256, 256, 0, stream>>>(x, xb, NN * 128 / 4);
    transpose_cast<<<(256 * 128 + 255) / 256, 256, 0, stream>>>(W0, Wt0, 128, 256);
    transpose_cast<<<(256 * 256 + 255) / 256, 256, 0, stream>>>(W1, Wt1, 256, 256);
    transpose_cast<<<(128 * 256 + 255) / 256, 256, 0, stream>>>(W2, Wt2, 256, 128);

    const int GM = (NN + 127) / 128;   // 782
    const int NB4 = (NN + 3) / 4;      // 25000

    // ---- layer 0
    gemm_bf16<<<dim3(GM, 2), 256, 0, stream>>>(xb, Wt0, h, NN, 128, 256);
    scores_k<4, 256><<<NB4, 256, 0, stream>>>(h, as0, ad0, als, ald);
    aggregate<4, 256, true, true><<<NB4, 256, 0, stream>>>(h, als, ald, row_ptr, col, b0, actB);

    // ---- layer 1
    gemm_bf16<<<dim3(GM, 2), 256, 0, stream>>>(actB, Wt1, h, NN, 256, 256);
    scores_k<4, 256><<<NB4, 256, 0, stream>>>(h, as1, ad1, als, ald);
    aggregate<4, 256, true, true><<<NB4, 256, 0, stream>>>(h, als, ald, row_ptr, col, b1, actC);

    // ---- layer 2
    gemm_bf16<<<dim3(GM, 1), 256, 0, stream>>>(actC, Wt2, h, NN, 256, 128);
    scores_k<1, 128><<<NB4, 256, 0, stream>>>(h, as2, ad2, als, ald);
    aggregate<1, 128, false, false><<<NB4, 256, 0, stream>>>(h, als, ald, row_ptr, col, b2, out);
}